// Round 9
// baseline (717.960 us; speedup 1.0000x reference)
//
#include <hip/hip_runtime.h>
#include <hip/hip_bf16.h>

typedef __attribute__((ext_vector_type(4))) float f32x4;
typedef _Float16 f16;
typedef __attribute__((ext_vector_type(8))) _Float16 f16x8;
typedef __attribute__((ext_vector_type(4))) _Float16 f16x4;
typedef __attribute__((ext_vector_type(2))) __fp16 pk16x2;   // cvt_pkrtz native return

#define S_LEN 2048
#define D_DIM 128
#define QBLK 256
#define KVBLK 64
#define NKV (S_LEN / KVBLK)

// softmax(x2 @ x3^T) @ x3 ; Q = x2, K = V = x3, no scale. fp16 MFMA path.
// 8 waves x 32 q-rows (2 x 16-q subtiles per wave): every K/V LDS read feeds
// two MFMAs (round-8 win), and 64 KB LDS -> 2 blocks/CU = 16 waves/CU for
// double the TLP of round 8 (which was concurrency-bound: no pipe >50%).
__global__ __launch_bounds__(512, 4) void attn_kernel(
    const float* __restrict__ Q, const float* __restrict__ KV,
    float* __restrict__ Out)
{
    // XCD-aware swizzle: 512 blocks % 8 == 0 -> bijective chunked map.
    unsigned b = blockIdx.x;
    unsigned cpx = gridDim.x >> 3;               // 64
    unsigned work = (b & 7u) * cpx + (b >> 3);
    unsigned head = work >> 3;                   // 64 heads
    unsigned qt = work & 7u;                     // 8 q-tiles per head

    const float* Qh = Q + (size_t)head * (S_LEN * D_DIM) + (size_t)qt * QBLK * D_DIM;
    const float* Kh = KV + (size_t)head * (S_LEN * D_DIM);
    float* Oh = Out + (size_t)head * (S_LEN * D_DIM) + (size_t)qt * QBLK * D_DIM;

    const int tid = threadIdx.x;
    const int wv = tid >> 6;        // 0..7
    const int lane = tid & 63;
    const int lo = lane & 15;
    const int hi = lane >> 4;

    // 16 + 16 + 32 = 64 KB -> 2 blocks/CU (160 KB LDS), 16 waves/CU.
    __shared__ __align__(16) f16 Ksh[KVBLK * D_DIM];      // [kv][d], swizzled
    __shared__ __align__(16) f16 Vsh[D_DIM * KVBLK];      // [d][kv] transposed, swizzled
    __shared__ __align__(16) f16 Psh[8][2][16 * KVBLK];   // per-wave, per-qsub [q][kv]

    // staging map: thread owns 4 rows x 4 cols of the 64x128 K/V tile
    const int srow = (tid >> 5) * 4;   // 0,4,..60
    const int scol = (tid & 31) * 4;   // 0,4,..124

    // ---- Q fragments for 2 q-subtiles: Q[wv*32 + t*16 + lo][kc*32 + hi*8 + j] ----
    f16x8 qf[2][4];
    #pragma unroll
    for (int t = 0; t < 2; ++t) {
        const float* qr = Qh + (wv * 32 + t * 16 + lo) * D_DIM + hi * 8;
        #pragma unroll
        for (int kc = 0; kc < 4; ++kc) {
            f32x4 a = *(const f32x4*)(qr + kc * 32);
            f32x4 c = *(const f32x4*)(qr + kc * 32 + 4);
            pk16x2 p0 = __builtin_amdgcn_cvt_pkrtz(a[0], a[1]);
            pk16x2 p1 = __builtin_amdgcn_cvt_pkrtz(a[2], a[3]);
            pk16x2 p2 = __builtin_amdgcn_cvt_pkrtz(c[0], c[1]);
            pk16x2 p3 = __builtin_amdgcn_cvt_pkrtz(c[2], c[3]);
            f16x8 q;
            q[0] = (f16)p0[0]; q[1] = (f16)p0[1]; q[2] = (f16)p1[0]; q[3] = (f16)p1[1];
            q[4] = (f16)p2[0]; q[5] = (f16)p2[1]; q[6] = (f16)p3[0]; q[7] = (f16)p3[1];
            qf[t][kc] = q;
        }
    }

    f32x4 oacc[2][8];
    #pragma unroll
    for (int t = 0; t < 2; ++t)
        #pragma unroll
        for (int n = 0; n < 8; ++n) oacc[t][n] = (f32x4){0.f, 0.f, 0.f, 0.f};
    float mr[2] = {-1e30f, -1e30f};
    float lr[2] = {0.f, 0.f};

    f32x4 stg[4];

    #define STAGE_LOAD(KT) do {                                               \
        const float* p_ = Kh + (size_t)(KT) * KVBLK * D_DIM + srow * D_DIM + scol; \
        _Pragma("unroll")                                                     \
        for (int i_ = 0; i_ < 4; ++i_) stg[i_] = *(const f32x4*)(p_ + i_ * D_DIM); \
    } while (0)

    #define STAGE_WRITE() do {                                                \
        _Pragma("unroll")                                                     \
        for (int i_ = 0; i_ < 4; ++i_) {                                      \
            int row_ = srow + i_;                                             \
            int fK_ = (row_ & 7) ^ ((row_ >> 3) & 7);                         \
            pk16x2 a_ = __builtin_amdgcn_cvt_pkrtz(stg[i_][0], stg[i_][1]);   \
            pk16x2 b_ = __builtin_amdgcn_cvt_pkrtz(stg[i_][2], stg[i_][3]);   \
            f16x4 w_;                                                         \
            w_[0] = (f16)a_[0]; w_[1] = (f16)a_[1];                           \
            w_[2] = (f16)b_[0]; w_[3] = (f16)b_[1];                           \
            *(f16x4*)&Ksh[row_ * D_DIM + (scol ^ (fK_ << 3))] = w_;           \
        }                                                                     \
        _Pragma("unroll")                                                     \
        for (int j_ = 0; j_ < 4; ++j_) {                                      \
            int d_ = scol + j_;                                               \
            int g_ = (d_ & 7) ^ ((d_ >> 3) & 7);                              \
            pk16x2 a0_ = __builtin_amdgcn_cvt_pkrtz(stg[0][j_], stg[1][j_]);  \
            pk16x2 a1_ = __builtin_amdgcn_cvt_pkrtz(stg[2][j_], stg[3][j_]);  \
            f16x4 w_;                                                         \
            w_[0] = (f16)a0_[0]; w_[1] = (f16)a0_[1];                         \
            w_[2] = (f16)a1_[0]; w_[3] = (f16)a1_[1];                         \
            *(f16x4*)&Vsh[d_ * KVBLK + (srow ^ (g_ << 3))] = w_;              \
        }                                                                     \
    } while (0)

    // prologue: tile 0
    STAGE_LOAD(0);
    STAGE_WRITE();
    __syncthreads();

    for (int kt = 0; kt < NKV; ++kt) {
        // issue next tile's global loads early; consumed after the barrier
        if (kt + 1 < NKV) STAGE_LOAD(kt + 1);

        // ---- swapped QK^T: S^T = K_tile @ Q^T, one kf read -> 2 MFMAs ----
        f32x4 st[2][4];
        #pragma unroll
        for (int t = 0; t < 2; ++t)
            #pragma unroll
            for (int m = 0; m < 4; ++m) st[t][m] = (f32x4){0.f, 0.f, 0.f, 0.f};
        __builtin_amdgcn_s_setprio(1);
        #pragma unroll
        for (int m = 0; m < 4; ++m) {
            int row = m * 16 + lo;
            int fK = (row & 7) ^ ((row >> 3) & 7);
            #pragma unroll
            for (int kc = 0; kc < 4; ++kc) {
                f16x8 kf = *(const f16x8*)&Ksh[row * D_DIM + ((kc * 32 + hi * 8) ^ (fK << 3))];
                st[0][m] = __builtin_amdgcn_mfma_f32_16x16x32_f16(kf, qf[0][kc], st[0][m], 0, 0, 0);
                st[1][m] = __builtin_amdgcn_mfma_f32_16x16x32_f16(kf, qf[1][kc], st[1][m], 0, 0, 0);
            }
        }
        __builtin_amdgcn_s_setprio(0);
        // lane holds S^T[kv = m*16 + hi*4 + r][q = wv*32 + t*16 + lo]

        // ---- online softmax per q-subtile, T13 defer-max (THR=8) ----
        const int swp = (lo & 7) << 3;
        #pragma unroll
        for (int t = 0; t < 2; ++t) {
            float tmax = -1e30f;
            #pragma unroll
            for (int m = 0; m < 4; ++m)
                #pragma unroll
                for (int r = 0; r < 4; ++r) tmax = fmaxf(tmax, st[t][m][r]);
            tmax = fmaxf(tmax, __shfl_xor(tmax, 16, 64));
            tmax = fmaxf(tmax, __shfl_xor(tmax, 32, 64));

            bool skip = __all(tmax - mr[t] <= 8.0f);
            float mnew = skip ? mr[t] : fmaxf(mr[t], tmax);

            float ls = 0.f;
            #pragma unroll
            for (int m = 0; m < 4; ++m) {
                #pragma unroll
                for (int r = 0; r < 4; ++r) {
                    float p = __expf(st[t][m][r] - mnew);
                    st[t][m][r] = p;
                    ls += p;
                }
            }
            ls += __shfl_xor(ls, 16, 64);
            ls += __shfl_xor(ls, 32, 64);

            if (!skip) {
                float scale = __expf(mr[t] - mnew);
                lr[t] = lr[t] * scale + ls;
                float sc4[4];
                #pragma unroll
                for (int r = 0; r < 4; ++r) sc4[r] = __shfl(scale, hi * 4 + r, 64);
                #pragma unroll
                for (int n = 0; n < 8; ++n)
                    #pragma unroll
                    for (int r = 0; r < 4; ++r) oacc[t][n][r] *= sc4[r];
                mr[t] = mnew;
            } else {
                lr[t] += ls;
            }

            // ---- P -> LDS (fp16), per-wave per-subtile buffer ----
            #pragma unroll
            for (int m = 0; m < 4; ++m) {
                pk16x2 a2 = __builtin_amdgcn_cvt_pkrtz(st[t][m][0], st[t][m][1]);
                pk16x2 b2 = __builtin_amdgcn_cvt_pkrtz(st[t][m][2], st[t][m][3]);
                f16x4 w;
                w[0] = (f16)a2[0]; w[1] = (f16)a2[1]; w[2] = (f16)b2[0]; w[3] = (f16)b2[1];
                int col = (m * 16 + hi * 4) ^ swp;
                *(f16x4*)&Psh[wv][t][lo * KVBLK + col] = w;
            }
        }

        // ---- PV: O += P @ V, one vf read -> 2 MFMAs ----
        __builtin_amdgcn_s_setprio(1);
        #pragma unroll
        for (int kc2 = 0; kc2 < 2; ++kc2) {
            f16x8 pf0 = *(const f16x8*)&Psh[wv][0][lo * KVBLK + ((kc2 * 32 + hi * 8) ^ swp)];
            f16x8 pf1 = *(const f16x8*)&Psh[wv][1][lo * KVBLK + ((kc2 * 32 + hi * 8) ^ swp)];
            #pragma unroll
            for (int n = 0; n < 8; ++n) {
                int d = n * 16 + lo;
                int g = (d & 7) ^ ((d >> 3) & 7);
                f16x8 vf = *(const f16x8*)&Vsh[d * KVBLK + ((kc2 * 32 + hi * 8) ^ (g << 3))];
                oacc[0][n] = __builtin_amdgcn_mfma_f32_16x16x32_f16(pf0, vf, oacc[0][n], 0, 0, 0);
                oacc[1][n] = __builtin_amdgcn_mfma_f32_16x16x32_f16(pf1, vf, oacc[1][n], 0, 0, 0);
            }
        }
        __builtin_amdgcn_s_setprio(0);

        __syncthreads();                    // all waves done reading Ksh/Vsh
        if (kt + 1 < NKV) {
            STAGE_WRITE();                  // overwrite with next tile
            __syncthreads();                // next tile visible to all
        }
    }

    // ---- epilogue: O / l, write fp32 ----
    #pragma unroll
    for (int t = 0; t < 2; ++t) {
        float inv = 1.0f / lr[t];   // valid at lane's q = lo
        float rl[4];
        #pragma unroll
        for (int r = 0; r < 4; ++r) rl[r] = __shfl(inv, hi * 4 + r, 64);
        #pragma unroll
        for (int n = 0; n < 8; ++n)
            #pragma unroll
            for (int r = 0; r < 4; ++r)
                Oh[(wv * 32 + t * 16 + hi * 4 + r) * D_DIM + n * 16 + lo] = oacc[t][n][r] * rl[r];
    }
}

extern "C" void kernel_launch(void* const* d_in, const int* in_sizes, int n_in,
                              void* d_out, int out_size, void* d_ws, size_t ws_size,
                              hipStream_t stream) {
    const float* x2 = (const float*)d_in[0];
    const float* x3 = (const float*)d_in[1];
    float* out = (float*)d_out;
    dim3 grid(512), block(512);
    hipLaunchKernelGGL(attn_kernel, grid, block, 0, stream, x2, x3, out);
}

// Round 10
// 177.468 us; speedup vs baseline: 4.0456x; 4.0456x over previous
//
#include <hip/hip_runtime.h>
#include <hip/hip_bf16.h>

typedef __attribute__((ext_vector_type(4))) float f32x4;
typedef _Float16 f16;
typedef __attribute__((ext_vector_type(8))) _Float16 f16x8;
typedef __attribute__((ext_vector_type(4))) _Float16 f16x4;
typedef __attribute__((ext_vector_type(2))) __fp16 pk16x2;   // cvt_pkrtz native return

#define S_LEN 2048
#define D_DIM 128
#define QBLK 128
#define KVBLK 64
#define NKV (S_LEN / KVBLK)

// softmax(x2 @ x3^T) @ x3 ; Q = x2, K = V = x3, no scale. fp16 MFMA path.
// Round-8 structure (4 waves x 32 q-rows, one K/V read feeds 2 MFMAs) +
// K/V DOUBLE-BUFFER: one barrier per tile, stage-write overlaps PV drain.
// Register rule (rounds 6 & 9): 256-thr blocks with (256,2) ONLY — tighter
// bounds cap the unified VGPR/AGPR file below ~200 demand -> scratch spill.
__global__ __launch_bounds__(256, 2) void attn_kernel(
    const float* __restrict__ Q, const float* __restrict__ KV,
    float* __restrict__ Out)
{
    // XCD-aware swizzle: 1024 blocks % 8 == 0 -> bijective chunked map.
    unsigned b = blockIdx.x;
    unsigned cpx = gridDim.x >> 3;               // 128
    unsigned work = (b & 7u) * cpx + (b >> 3);
    unsigned head = work >> 4;                   // 64 heads
    unsigned qt = work & 15u;                    // 16 q-tiles per head

    const float* Qh = Q + (size_t)head * (S_LEN * D_DIM) + (size_t)qt * QBLK * D_DIM;
    const float* Kh = KV + (size_t)head * (S_LEN * D_DIM);
    float* Oh = Out + (size_t)head * (S_LEN * D_DIM) + (size_t)qt * QBLK * D_DIM;

    const int tid = threadIdx.x;
    const int wv = tid >> 6;        // 0..3
    const int lane = tid & 63;
    const int lo = lane & 15;
    const int hi = lane >> 4;

    // 2*16 + 2*16 + 16 = 80 KB -> 2 blocks/CU (reg-bound at 2 regardless).
    __shared__ __align__(16) f16 Ksh[2][KVBLK * D_DIM];   // [buf][kv][d], swizzled
    __shared__ __align__(16) f16 Vsh[2][D_DIM * KVBLK];   // [buf][d][kv] transposed, swizzled
    __shared__ __align__(16) f16 Psh[4][2][16 * KVBLK];   // per-wave, per-qsub [q][kv]

    // staging map: thread owns 8 rows x 4 cols (rows srow.., cols scol..)
    const int srow = (tid >> 5) * 8;   // 0,8,..56
    const int scol = (tid & 31) * 4;   // 0,4,..124

    // ---- Q fragments for 2 q-subtiles: Q[wv*32 + t*16 + lo][kc*32 + hi*8 + j] ----
    f16x8 qf[2][4];
    #pragma unroll
    for (int t = 0; t < 2; ++t) {
        const float* qr = Qh + (wv * 32 + t * 16 + lo) * D_DIM + hi * 8;
        #pragma unroll
        for (int kc = 0; kc < 4; ++kc) {
            f32x4 a = *(const f32x4*)(qr + kc * 32);
            f32x4 c = *(const f32x4*)(qr + kc * 32 + 4);
            pk16x2 p0 = __builtin_amdgcn_cvt_pkrtz(a[0], a[1]);
            pk16x2 p1 = __builtin_amdgcn_cvt_pkrtz(a[2], a[3]);
            pk16x2 p2 = __builtin_amdgcn_cvt_pkrtz(c[0], c[1]);
            pk16x2 p3 = __builtin_amdgcn_cvt_pkrtz(c[2], c[3]);
            f16x8 q;
            q[0] = (f16)p0[0]; q[1] = (f16)p0[1]; q[2] = (f16)p1[0]; q[3] = (f16)p1[1];
            q[4] = (f16)p2[0]; q[5] = (f16)p2[1]; q[6] = (f16)p3[0]; q[7] = (f16)p3[1];
            qf[t][kc] = q;
        }
    }

    f32x4 oacc[2][8];
    #pragma unroll
    for (int t = 0; t < 2; ++t)
        #pragma unroll
        for (int n = 0; n < 8; ++n) oacc[t][n] = (f32x4){0.f, 0.f, 0.f, 0.f};
    float mr[2] = {-1e30f, -1e30f};
    float lr[2] = {0.f, 0.f};

    f32x4 stg[8];

    #define STAGE_LOAD(KT) do {                                               \
        const float* p_ = Kh + (size_t)(KT) * KVBLK * D_DIM + srow * D_DIM + scol; \
        _Pragma("unroll")                                                     \
        for (int i_ = 0; i_ < 8; ++i_) stg[i_] = *(const f32x4*)(p_ + i_ * D_DIM); \
    } while (0)

    #define STAGE_WRITE(BUF) do {                                             \
        _Pragma("unroll")                                                     \
        for (int i_ = 0; i_ < 8; ++i_) {                                      \
            int row_ = srow + i_;                                             \
            int fK_ = (row_ & 7) ^ ((row_ >> 3) & 7);                         \
            pk16x2 a_ = __builtin_amdgcn_cvt_pkrtz(stg[i_][0], stg[i_][1]);   \
            pk16x2 b_ = __builtin_amdgcn_cvt_pkrtz(stg[i_][2], stg[i_][3]);   \
            f16x4 w_;                                                         \
            w_[0] = (f16)a_[0]; w_[1] = (f16)a_[1];                           \
            w_[2] = (f16)b_[0]; w_[3] = (f16)b_[1];                           \
            *(f16x4*)&Ksh[BUF][row_ * D_DIM + (scol ^ (fK_ << 3))] = w_;      \
        }                                                                     \
        _Pragma("unroll")                                                     \
        for (int j_ = 0; j_ < 4; ++j_) {                                      \
            int d_ = scol + j_;                                               \
            int g_ = (d_ & 7) ^ ((d_ >> 3) & 7);                              \
            pk16x2 a0_ = __builtin_amdgcn_cvt_pkrtz(stg[0][j_], stg[1][j_]);  \
            pk16x2 a1_ = __builtin_amdgcn_cvt_pkrtz(stg[2][j_], stg[3][j_]);  \
            pk16x2 a2_ = __builtin_amdgcn_cvt_pkrtz(stg[4][j_], stg[5][j_]);  \
            pk16x2 a3_ = __builtin_amdgcn_cvt_pkrtz(stg[6][j_], stg[7][j_]);  \
            f16x8 w_;                                                         \
            w_[0] = (f16)a0_[0]; w_[1] = (f16)a0_[1];                         \
            w_[2] = (f16)a1_[0]; w_[3] = (f16)a1_[1];                         \
            w_[4] = (f16)a2_[0]; w_[5] = (f16)a2_[1];                         \
            w_[6] = (f16)a3_[0]; w_[7] = (f16)a3_[1];                         \
            *(f16x8*)&Vsh[BUF][d_ * KVBLK + (srow ^ (g_ << 3))] = w_;         \
        }                                                                     \
    } while (0)

    // prologue: tile 0 into buf 0
    STAGE_LOAD(0);
    STAGE_WRITE(0);
    __syncthreads();

    for (int kt = 0; kt < NKV; ++kt) {
        const int cur = kt & 1;
        // issue next tile's global loads early; written to buf cur^1 below
        if (kt + 1 < NKV) STAGE_LOAD(kt + 1);

        // ---- swapped QK^T: S^T = K_tile @ Q^T, one kf read -> 2 MFMAs ----
        f32x4 st[2][4];
        #pragma unroll
        for (int t = 0; t < 2; ++t)
            #pragma unroll
            for (int m = 0; m < 4; ++m) st[t][m] = (f32x4){0.f, 0.f, 0.f, 0.f};
        __builtin_amdgcn_s_setprio(1);
        #pragma unroll
        for (int m = 0; m < 4; ++m) {
            int row = m * 16 + lo;
            int fK = (row & 7) ^ ((row >> 3) & 7);
            #pragma unroll
            for (int kc = 0; kc < 4; ++kc) {
                f16x8 kf = *(const f16x8*)&Ksh[cur][row * D_DIM + ((kc * 32 + hi * 8) ^ (fK << 3))];
                st[0][m] = __builtin_amdgcn_mfma_f32_16x16x32_f16(kf, qf[0][kc], st[0][m], 0, 0, 0);
                st[1][m] = __builtin_amdgcn_mfma_f32_16x16x32_f16(kf, qf[1][kc], st[1][m], 0, 0, 0);
            }
        }
        __builtin_amdgcn_s_setprio(0);
        // lane holds S^T[kv = m*16 + hi*4 + r][q = wv*32 + t*16 + lo]

        // ---- online softmax per q-subtile, T13 defer-max (THR=8) ----
        const int swp = (lo & 7) << 3;
        #pragma unroll
        for (int t = 0; t < 2; ++t) {
            float tmax = -1e30f;
            #pragma unroll
            for (int m = 0; m < 4; ++m)
                #pragma unroll
                for (int r = 0; r < 4; ++r) tmax = fmaxf(tmax, st[t][m][r]);
            tmax = fmaxf(tmax, __shfl_xor(tmax, 16, 64));
            tmax = fmaxf(tmax, __shfl_xor(tmax, 32, 64));

            bool skip = __all(tmax - mr[t] <= 8.0f);
            float mnew = skip ? mr[t] : fmaxf(mr[t], tmax);

            float ls = 0.f;
            #pragma unroll
            for (int m = 0; m < 4; ++m) {
                #pragma unroll
                for (int r = 0; r < 4; ++r) {
                    float p = __expf(st[t][m][r] - mnew);
                    st[t][m][r] = p;
                    ls += p;
                }
            }
            ls += __shfl_xor(ls, 16, 64);
            ls += __shfl_xor(ls, 32, 64);

            if (!skip) {
                float scale = __expf(mr[t] - mnew);
                lr[t] = lr[t] * scale + ls;
                float sc4[4];
                #pragma unroll
                for (int r = 0; r < 4; ++r) sc4[r] = __shfl(scale, hi * 4 + r, 64);
                #pragma unroll
                for (int n = 0; n < 8; ++n)
                    #pragma unroll
                    for (int r = 0; r < 4; ++r) oacc[t][n][r] *= sc4[r];
                mr[t] = mnew;
            } else {
                lr[t] += ls;
            }

            // ---- P -> LDS (fp16), per-wave per-subtile buffer ----
            #pragma unroll
            for (int m = 0; m < 4; ++m) {
                pk16x2 a2 = __builtin_amdgcn_cvt_pkrtz(st[t][m][0], st[t][m][1]);
                pk16x2 b2 = __builtin_amdgcn_cvt_pkrtz(st[t][m][2], st[t][m][3]);
                f16x4 w;
                w[0] = (f16)a2[0]; w[1] = (f16)a2[1]; w[2] = (f16)b2[0]; w[3] = (f16)b2[1];
                int col = (m * 16 + hi * 4) ^ swp;
                *(f16x4*)&Psh[wv][t][lo * KVBLK + col] = w;
            }
        }

        // ---- PV: O += P @ V, one vf read -> 2 MFMAs ----
        __builtin_amdgcn_s_setprio(1);
        #pragma unroll
        for (int kc2 = 0; kc2 < 2; ++kc2) {
            f16x8 pf0 = *(const f16x8*)&Psh[wv][0][lo * KVBLK + ((kc2 * 32 + hi * 8) ^ swp)];
            f16x8 pf1 = *(const f16x8*)&Psh[wv][1][lo * KVBLK + ((kc2 * 32 + hi * 8) ^ swp)];
            #pragma unroll
            for (int n = 0; n < 8; ++n) {
                int d = n * 16 + lo;
                int g = (d & 7) ^ ((d >> 3) & 7);
                f16x8 vf = *(const f16x8*)&Vsh[cur][d * KVBLK + ((kc2 * 32 + hi * 8) ^ (g << 3))];
                oacc[0][n] = __builtin_amdgcn_mfma_f32_16x16x32_f16(pf0, vf, oacc[0][n], 0, 0, 0);
                oacc[1][n] = __builtin_amdgcn_mfma_f32_16x16x32_f16(pf1, vf, oacc[1][n], 0, 0, 0);
            }
        }
        __builtin_amdgcn_s_setprio(0);

        // ---- write next tile into the other buffer; ONE barrier per tile ----
        if (kt + 1 < NKV) STAGE_WRITE(cur ^ 1);
        __syncthreads();
    }

    // ---- epilogue: O / l, write fp32 ----
    #pragma unroll
    for (int t = 0; t < 2; ++t) {
        float inv = 1.0f / lr[t];   // valid at lane's q = lo
        float rl[4];
        #pragma unroll
        for (int r = 0; r < 4; ++r) rl[r] = __shfl(inv, hi * 4 + r, 64);
        #pragma unroll
        for (int n = 0; n < 8; ++n)
            #pragma unroll
            for (int r = 0; r < 4; ++r)
                Oh[(wv * 32 + t * 16 + hi * 4 + r) * D_DIM + n * 16 + lo] = oacc[t][n][r] * rl[r];
    }
}

extern "C" void kernel_launch(void* const* d_in, const int* in_sizes, int n_in,
                              void* d_out, int out_size, void* d_ws, size_t ws_size,
                              hipStream_t stream) {
    const float* x2 = (const float*)d_in[0];
    const float* x3 = (const float*)d_in[1];
    float* out = (float*)d_out;
    dim3 grid(1024), block(256);
    hipLaunchKernelGGL(attn_kernel, grid, block, 0, stream, x2, x3, out);
}

// Round 12
// 169.956 us; speedup vs baseline: 4.2244x; 1.0442x over previous
//
#include <hip/hip_runtime.h>
#include <hip/hip_bf16.h>

typedef __attribute__((ext_vector_type(4))) float f32x4;
typedef _Float16 f16;
typedef __attribute__((ext_vector_type(8))) _Float16 f16x8;
typedef __attribute__((ext_vector_type(4))) _Float16 f16x4;
typedef __attribute__((ext_vector_type(2))) __fp16 pk16x2;       // cvt_pkrtz native return
typedef __attribute__((ext_vector_type(2))) unsigned int uint2v; // permlane*_swap return

#define S_LEN 2048
#define D_DIM 128
#define QBLK 128
#define KVBLK 64
#define NKV (S_LEN / KVBLK)

// reduce over the 4 hi-groups (lanes sharing lo) via permlane swaps (VALU,
// off the LDS pipe). Builtins return {new_vdst,new_vsrc} — no aliasing hazard
// (round-11 inline-asm version let the compiler coalesce the two operands).
__device__ __forceinline__ float hired_max(float x) {
    uint2v s = __builtin_amdgcn_permlane16_swap(__float_as_uint(x), __float_as_uint(x), false, false);
    float m = fmaxf(__uint_as_float(s.x), __uint_as_float(s.y));
    uint2v s2 = __builtin_amdgcn_permlane32_swap(__float_as_uint(m), __float_as_uint(m), false, false);
    return fmaxf(__uint_as_float(s2.x), __uint_as_float(s2.y));
}
__device__ __forceinline__ float hired_sum(float x) {
    uint2v s = __builtin_amdgcn_permlane16_swap(__float_as_uint(x), __float_as_uint(x), false, false);
    float m = __uint_as_float(s.x) + __uint_as_float(s.y);
    uint2v s2 = __builtin_amdgcn_permlane32_swap(__float_as_uint(m), __float_as_uint(m), false, false);
    return __uint_as_float(s2.x) + __uint_as_float(s2.y);
}

// softmax(x2 @ x3^T) @ x3 ; Q = x2, K = V = x3, no scale. fp16 MFMA path.
// Round-8 structure (4 waves x 32 q, one K/V LDS read -> 2 MFMAs) + T12:
// P stays in registers — packed to fp16, then a 4-op permlane16/32_swap
// network per (t,kc2) converts QK^T output layout into the PV A-fragment.
// LDS = K 16KB + V 16KB only (Psh deleted).
__global__ __launch_bounds__(256, 2) void attn_kernel(
    const float* __restrict__ Q, const float* __restrict__ KV,
    float* __restrict__ Out)
{
    // XCD-aware swizzle: 1024 blocks % 8 == 0 -> bijective chunked map.
    unsigned b = blockIdx.x;
    unsigned cpx = gridDim.x >> 3;               // 128
    unsigned work = (b & 7u) * cpx + (b >> 3);
    unsigned head = work >> 4;                   // 64 heads
    unsigned qt = work & 15u;                    // 16 q-tiles per head

    const float* Qh = Q + (size_t)head * (S_LEN * D_DIM) + (size_t)qt * QBLK * D_DIM;
    const float* Kh = KV + (size_t)head * (S_LEN * D_DIM);
    float* Oh = Out + (size_t)head * (S_LEN * D_DIM) + (size_t)qt * QBLK * D_DIM;

    const int tid = threadIdx.x;
    const int wv = tid >> 6;        // 0..3
    const int lane = tid & 63;
    const int lo = lane & 15;
    const int hi = lane >> 4;

    // 16 + 16 = 32 KB
    __shared__ __align__(16) f16 Ksh[KVBLK * D_DIM];      // [kv][d], swizzled
    __shared__ __align__(16) f16 Vsh[D_DIM * KVBLK];      // [d][kv] transposed, swizzled

    // staging map: thread owns 8 rows x 4 cols (rows srow.., cols scol..)
    const int srow = (tid >> 5) * 8;   // 0,8,..56
    const int scol = (tid & 31) * 4;   // 0,4,..124

    // ---- Q fragments for 2 q-subtiles: Q[wv*32 + t*16 + lo][kc*32 + hi*8 + j] ----
    f16x8 qf[2][4];
    #pragma unroll
    for (int t = 0; t < 2; ++t) {
        const float* qr = Qh + (wv * 32 + t * 16 + lo) * D_DIM + hi * 8;
        #pragma unroll
        for (int kc = 0; kc < 4; ++kc) {
            f32x4 a = *(const f32x4*)(qr + kc * 32);
            f32x4 c = *(const f32x4*)(qr + kc * 32 + 4);
            pk16x2 p0 = __builtin_amdgcn_cvt_pkrtz(a[0], a[1]);
            pk16x2 p1 = __builtin_amdgcn_cvt_pkrtz(a[2], a[3]);
            pk16x2 p2 = __builtin_amdgcn_cvt_pkrtz(c[0], c[1]);
            pk16x2 p3 = __builtin_amdgcn_cvt_pkrtz(c[2], c[3]);
            f16x8 q;
            q[0] = (f16)p0[0]; q[1] = (f16)p0[1]; q[2] = (f16)p1[0]; q[3] = (f16)p1[1];
            q[4] = (f16)p2[0]; q[5] = (f16)p2[1]; q[6] = (f16)p3[0]; q[7] = (f16)p3[1];
            qf[t][kc] = q;
        }
    }

    f32x4 oacc[2][8];
    #pragma unroll
    for (int t = 0; t < 2; ++t)
        #pragma unroll
        for (int n = 0; n < 8; ++n) oacc[t][n] = (f32x4){0.f, 0.f, 0.f, 0.f};
    float mr[2] = {-1e30f, -1e30f};
    float lr[2] = {0.f, 0.f};

    f32x4 stg[8];

    #define STAGE_LOAD(KT) do {                                               \
        const float* p_ = Kh + (size_t)(KT) * KVBLK * D_DIM + srow * D_DIM + scol; \
        _Pragma("unroll")                                                     \
        for (int i_ = 0; i_ < 8; ++i_) stg[i_] = *(const f32x4*)(p_ + i_ * D_DIM); \
    } while (0)

    #define STAGE_WRITE() do {                                                \
        _Pragma("unroll")                                                     \
        for (int i_ = 0; i_ < 8; ++i_) {                                      \
            int row_ = srow + i_;                                             \
            int fK_ = (row_ & 7) ^ ((row_ >> 3) & 7);                         \
            pk16x2 a_ = __builtin_amdgcn_cvt_pkrtz(stg[i_][0], stg[i_][1]);   \
            pk16x2 b_ = __builtin_amdgcn_cvt_pkrtz(stg[i_][2], stg[i_][3]);   \
            f16x4 w_;                                                         \
            w_[0] = (f16)a_[0]; w_[1] = (f16)a_[1];                           \
            w_[2] = (f16)b_[0]; w_[3] = (f16)b_[1];                           \
            *(f16x4*)&Ksh[row_ * D_DIM + (scol ^ (fK_ << 3))] = w_;           \
        }                                                                     \
        _Pragma("unroll")                                                     \
        for (int j_ = 0; j_ < 4; ++j_) {                                      \
            int d_ = scol + j_;                                               \
            int g_ = (d_ & 7) ^ ((d_ >> 3) & 7);                              \
            pk16x2 a0_ = __builtin_amdgcn_cvt_pkrtz(stg[0][j_], stg[1][j_]);  \
            pk16x2 a1_ = __builtin_amdgcn_cvt_pkrtz(stg[2][j_], stg[3][j_]);  \
            pk16x2 a2_ = __builtin_amdgcn_cvt_pkrtz(stg[4][j_], stg[5][j_]);  \
            pk16x2 a3_ = __builtin_amdgcn_cvt_pkrtz(stg[6][j_], stg[7][j_]);  \
            f16x8 w_;                                                         \
            w_[0] = (f16)a0_[0]; w_[1] = (f16)a0_[1];                         \
            w_[2] = (f16)a1_[0]; w_[3] = (f16)a1_[1];                         \
            w_[4] = (f16)a2_[0]; w_[5] = (f16)a2_[1];                         \
            w_[6] = (f16)a3_[0]; w_[7] = (f16)a3_[1];                         \
            *(f16x8*)&Vsh[d_ * KVBLK + (srow ^ (g_ << 3))] = w_;              \
        }                                                                     \
    } while (0)

    // prologue: tile 0
    STAGE_LOAD(0);
    STAGE_WRITE();
    __syncthreads();

    for (int kt = 0; kt < NKV; ++kt) {
        // issue next tile's global loads early; consumed after the barrier
        if (kt + 1 < NKV) STAGE_LOAD(kt + 1);

        // ---- swapped QK^T: S^T = K_tile @ Q^T, one kf read -> 2 MFMAs ----
        f32x4 st[2][4];
        #pragma unroll
        for (int t = 0; t < 2; ++t)
            #pragma unroll
            for (int m = 0; m < 4; ++m) st[t][m] = (f32x4){0.f, 0.f, 0.f, 0.f};
        __builtin_amdgcn_s_setprio(1);
        #pragma unroll
        for (int m = 0; m < 4; ++m) {
            int row = m * 16 + lo;
            int fK = (row & 7) ^ ((row >> 3) & 7);
            #pragma unroll
            for (int kc = 0; kc < 4; ++kc) {
                f16x8 kf = *(const f16x8*)&Ksh[row * D_DIM + ((kc * 32 + hi * 8) ^ (fK << 3))];
                st[0][m] = __builtin_amdgcn_mfma_f32_16x16x32_f16(kf, qf[0][kc], st[0][m], 0, 0, 0);
                st[1][m] = __builtin_amdgcn_mfma_f32_16x16x32_f16(kf, qf[1][kc], st[1][m], 0, 0, 0);
            }
        }
        __builtin_amdgcn_s_setprio(0);
        // lane holds S^T[kv = m*16 + hi*4 + r][q = wv*32 + t*16 + lo]

        // ---- softmax (permlane reductions) + in-register P re-layout ----
        f16x8 pf[2][2];
        #pragma unroll
        for (int t = 0; t < 2; ++t) {
            float tmax = -1e30f;
            #pragma unroll
            for (int m = 0; m < 4; ++m)
                #pragma unroll
                for (int r = 0; r < 4; ++r) tmax = fmaxf(tmax, st[t][m][r]);
            tmax = hired_max(tmax);

            bool skip = __all(tmax - mr[t] <= 8.0f);
            float mnew = skip ? mr[t] : fmaxf(mr[t], tmax);

            float ls = 0.f;
            #pragma unroll
            for (int m = 0; m < 4; ++m) {
                #pragma unroll
                for (int r = 0; r < 4; ++r) {
                    float p = __expf(st[t][m][r] - mnew);
                    st[t][m][r] = p;
                    ls += p;
                }
            }
            ls = hired_sum(ls);

            if (!skip) {
                float scale = __expf(mr[t] - mnew);
                lr[t] = lr[t] * scale + ls;
                float sc4[4];
                #pragma unroll
                for (int r = 0; r < 4; ++r) sc4[r] = __shfl(scale, hi * 4 + r, 64);
                #pragma unroll
                for (int n = 0; n < 8; ++n)
                    #pragma unroll
                    for (int r = 0; r < 4; ++r) oacc[t][n][r] *= sc4[r];
                mr[t] = mnew;
            } else {
                lr[t] += ls;
            }

            // pack P to fp16 pairs: cc[m][v] = f16x2(st[m][2v], st[m][2v+1])
            unsigned cc[4][2];
            #pragma unroll
            for (int m = 0; m < 4; ++m) {
                union { pk16x2 p; unsigned u; } ua, ub;
                ua.p = __builtin_amdgcn_cvt_pkrtz(st[t][m][0], st[t][m][1]);
                ub.p = __builtin_amdgcn_cvt_pkrtz(st[t][m][2], st[t][m][3]);
                cc[m][0] = ua.u; cc[m][1] = ub.u;
            }
            // re-layout to PV A-fragment: target lane (lo,hi) dword u must
            // hold P[kv=kc2*32+hi*8+2u+{0,1}][q=lo]. Verified network:
            // swap32(r0,r2), swap32(r1,r3) then swap16(r0,r2), swap16(r1,r3)
            // gives reg s, dword v at lane (b5,b4) = src reg (b5,v) at lane (b4,s).
            #pragma unroll
            for (int kc2 = 0; kc2 < 2; ++kc2) {
                unsigned r0 = cc[2 * kc2][0], r1 = cc[2 * kc2][1];
                unsigned r2 = cc[2 * kc2 + 1][0], r3 = cc[2 * kc2 + 1][1];
                uint2v s02 = __builtin_amdgcn_permlane32_swap(r0, r2, false, false);
                uint2v s13 = __builtin_amdgcn_permlane32_swap(r1, r3, false, false);
                uint2v t02 = __builtin_amdgcn_permlane16_swap(s02.x, s02.y, false, false);
                uint2v t13 = __builtin_amdgcn_permlane16_swap(s13.x, s13.y, false, false);
                union { unsigned u[4]; f16x8 v; } pu;
                pu.u[0] = t02.x; pu.u[1] = t13.x; pu.u[2] = t02.y; pu.u[3] = t13.y;
                pf[t][kc2] = pu.v;
            }
        }

        // ---- PV: O += P @ V, pf in registers, one vf read -> 2 MFMAs ----
        __builtin_amdgcn_s_setprio(1);
        #pragma unroll
        for (int kc2 = 0; kc2 < 2; ++kc2) {
            #pragma unroll
            for (int n = 0; n < 8; ++n) {
                int d = n * 16 + lo;
                int g = (d & 7) ^ ((d >> 3) & 7);
                f16x8 vf = *(const f16x8*)&Vsh[d * KVBLK + ((kc2 * 32 + hi * 8) ^ (g << 3))];
                oacc[0][n] = __builtin_amdgcn_mfma_f32_16x16x32_f16(pf[0][kc2], vf, oacc[0][n], 0, 0, 0);
                oacc[1][n] = __builtin_amdgcn_mfma_f32_16x16x32_f16(pf[1][kc2], vf, oacc[1][n], 0, 0, 0);
            }
        }
        __builtin_amdgcn_s_setprio(0);

        __syncthreads();                    // all waves done reading Ksh/Vsh
        if (kt + 1 < NKV) {
            STAGE_WRITE();                  // overwrite with next tile
            __syncthreads();                // next tile visible to all
        }
    }

    // ---- epilogue: O / l, write fp32 ----
    #pragma unroll
    for (int t = 0; t < 2; ++t) {
        float inv = 1.0f / lr[t];   // valid at lane's q = lo
        float rl[4];
        #pragma unroll
        for (int r = 0; r < 4; ++r) rl[r] = __shfl(inv, hi * 4 + r, 64);
        #pragma unroll
        for (int n = 0; n < 8; ++n)
            #pragma unroll
            for (int r = 0; r < 4; ++r)
                Oh[(wv * 32 + t * 16 + hi * 4 + r) * D_DIM + n * 16 + lo] = oacc[t][n][r] * rl[r];
    }
}

extern "C" void kernel_launch(void* const* d_in, const int* in_sizes, int n_in,
                              void* d_out, int out_size, void* d_ws, size_t ws_size,
                              hipStream_t stream) {
    const float* x2 = (const float*)d_in[0];
    const float* x3 = (const float*)d_in[1];
    float* out = (float*)d_out;
    dim3 grid(1024), block(256);
    hipLaunchKernelGGL(attn_kernel, grid, block, 0, stream, x2, x3, out);
}